// Round 1
// 159.277 us; speedup vs baseline: 1.0580x; 1.0580x over previous
//
#include <hip/hip_runtime.h>

#define BATCH 16
#define CH    16
#define HH    128
#define WW    128
#define NC    8            // n_convs
#define TR    8            // output rows per band
#define BPB   4            // bands per block (persistent over 4 bands)
#define HR    (TR + 2)     // 10 halo rows
#define FW    (WW + 2)     // 130 halo cols
#define NELEM (HR * FW)    // 1300 staged elements per band
#define NSTG  ((NELEM + 255) / 256)   // 6 staging slots per thread

// Per-element features: f0=silu(v), f1=tanh(v), f2=2t^2 (=T2+1), f3=T3=4t^3-3t.
// bias_j = sum_i (W0 - W2)[j,i] absorbs T0 and the +1 shift of f2, so features
// are exactly (0,0,0,0) at v=0 -> zero padding handled by feat(0)=0.
//
// Round-3 change: blocks are persistent over BPB=4 bands. Staging loads for
// band k+1 are issued into registers BEFORE band k's conv (own basic block, so
// the scheduler can't sink them below the FMAs); the vmcnt wait lands at the
// next iteration's feature-compute. This hides the global-load latency that
// previously serialized every band (rolled load->use->ds_write loop = 5-6
// dependent HBM round trips per wave per band, only 4 waves/SIMD to cover).
__global__ __launch_bounds__(256, 4)
void kan_conv_kernel(const float* __restrict__ x,
                     const float* __restrict__ cheby,   // (8,9,4)
                     const float* __restrict__ bwt,     // (8,9)
                     const float* __restrict__ scl,     // (8,9)
                     float* __restrict__ out)           // (16,128,128,128)
{
    __shared__ float4 feat[HR][FW];      // 20,800 B
    __shared__ float4 wgt[9 * NC];       // [tap*8 + j] = (bw, W1, W2, W3)
    __shared__ float  bias[NC];

    const int tid   = threadIdx.x;       // 0..255
    const int bz    = blockIdx.y;        // plane = b*CH + c
    const int band0 = blockIdx.x * (TR * BPB);

    const float* xp = x + (size_t)bz * HH * WW;

    // ---- stage combined weights (once per 4 bands now) ----
    if (tid < 9 * NC) {
        int j = tid / 9, i = tid % 9;
        float s = scl[j * 9 + i];
        wgt[i * NC + j] = make_float4(bwt[j * 9 + i],
                                      cheby[(j * 9 + i) * 4 + 1] * s,
                                      cheby[(j * 9 + i) * 4 + 2] * s,
                                      cheby[(j * 9 + i) * 4 + 3] * s);
    } else if (tid >= 128 && tid < 128 + NC) {
        int j = tid - 128;
        float b = 0.f;
        #pragma unroll
        for (int i = 0; i < 9; ++i)
            b += (cheby[(j * 9 + i) * 4 + 0] - cheby[(j * 9 + i) * 4 + 2]) * scl[j * 9 + i];
        bias[j] = b;
    }

    // ---- static staging coordinates (fully unrolled -> stays in registers) ----
    int srow[NSTG], scol[NSTG];
    #pragma unroll
    for (int k = 0; k < NSTG; ++k) {
        int idx = tid + 256 * k;
        srow[k] = idx / FW;
        scol[k] = idx - srow[k] * FW;
    }

    // ---- issue band-0 staging loads back-to-back into registers ----
    float v[NSTG];
    #pragma unroll
    for (int k = 0; k < NSTG; ++k) {
        int idx = tid + 256 * k;
        int gh  = band0 + srow[k] - 1;
        int gw  = scol[k] - 1;
        float nv = 0.f;
        if (idx < NELEM && (unsigned)gh < (unsigned)HH && (unsigned)gw < (unsigned)WW)
            nv = xp[gh * WW + gw];                        // 4B/lane coalesced
        v[k] = nv;
    }

    for (int bb = 0; bb < BPB; ++bb) {
        const int band = band0 + bb * TR;

        // ---- features from prefetched registers -> LDS ----
        // write stride = 16 B/lane -> canonical conflict-free b128 LDS pattern
        #pragma unroll
        for (int k = 0; k < NSTG; ++k) {
            int idx = tid + 256 * k;
            if (idx < NELEM) {
                float val = v[k];
                float e1 = __expf(val);
                float e2 = e1 * e1;                               // exp(2v)
                float sg = 1.f - __builtin_amdgcn_rcpf(1.f + e1); // sigmoid(v)
                float t  = 1.f - 2.f * __builtin_amdgcn_rcpf(e2 + 1.f); // tanh(v)
                float f2 = 2.f * t * t;                           // T2 + 1
                float f3 = 2.f * t * (f2 - 1.f) - t;              // T3
                feat[srow[k]][scol[k]] = make_float4(val * sg, t, f2, f3);
            }
        }
        __syncthreads();

        // ---- prefetch next band's x while this band's conv runs ----
        if (bb + 1 < BPB) {
            const int nb = band + TR;
            #pragma unroll
            for (int k = 0; k < NSTG; ++k) {
                int idx = tid + 256 * k;
                int gh  = nb + srow[k] - 1;
                int gw  = scol[k] - 1;
                float nv = 0.f;
                if (idx < NELEM && (unsigned)gh < (unsigned)HH && (unsigned)gw < (unsigned)WW)
                    nv = xp[gh * WW + gw];
                v[k] = nv;
            }
        }

        // ---- conv: thread owns col c, rows r0+2s (s=0..3); taps unrolled ----
        const int c  = tid & 127;            // 0..127
        const int r0 = tid >> 7;             // 0..1

        float acc[4][NC];                    // 32 VGPRs — fits, no spill
        #pragma unroll
        for (int s = 0; s < 4; ++s)
            #pragma unroll
            for (int j = 0; j < NC; ++j)
                acc[s][j] = bias[j];

        #pragma unroll
        for (int dr = 0; dr < 3; ++dr) {
            #pragma unroll
            for (int dc = 0; dc < 3; ++dc) {
                float4 f[4];
                #pragma unroll
                for (int s = 0; s < 4; ++s)
                    f[s] = feat[r0 + 2 * s + dr][c + dc];   // 16B/lane: conflict-free
                #pragma unroll
                for (int j = 0; j < NC; ++j) {
                    float4 w = wgt[(dr * 3 + dc) * NC + j]; // uniform broadcast
                    #pragma unroll
                    for (int s = 0; s < 4; ++s) {
                        acc[s][j] += w.x * f[s].x;
                        acc[s][j] += w.y * f[s].y;
                        acc[s][j] += w.z * f[s].z;
                        acc[s][j] += w.w * f[s].w;
                    }
                }
            }
        }

        // ---- store: each wave writes 64 consecutive floats (256B contiguous) ----
        float* op = out + (size_t)(bz * NC) * HH * WW + (size_t)(band + r0) * WW + c;
        #pragma unroll
        for (int j = 0; j < NC; ++j)
            #pragma unroll
            for (int s = 0; s < 4; ++s)
                op[(size_t)j * HH * WW + s * 2 * WW] = acc[s][j];

        __syncthreads();   // feat[] reuse guard for next band
    }
}

extern "C" void kernel_launch(void* const* d_in, const int* in_sizes, int n_in,
                              void* d_out, int out_size, void* d_ws, size_t ws_size,
                              hipStream_t stream) {
    const float* x     = (const float*)d_in[0];
    const float* cheby = (const float*)d_in[1];
    const float* bwt   = (const float*)d_in[2];
    const float* scl   = (const float*)d_in[3];
    float* out = (float*)d_out;

    dim3 grid(HH / (TR * BPB), BATCH * CH);  // 4 x 256 = 1024 persistent blocks
    dim3 block(256);
    hipLaunchKernelGGL(kan_conv_kernel, grid, block, 0, stream, x, cheby, bwt, scl, out);
}